// Round 4
// baseline (11057.717 us; speedup 1.0000x reference)
//
#include <hip/hip_runtime.h>

// DA-RNN persistent kernel, round 4: no nt hints (L3-resident streams),
// tanh-precomputed attention streams Tu/Td in [b][j][k] layout (half8 loads),
// tanh-identity score phase (1 transcendental/elem), o-pair x K-half split
// gate GEMVs with LDS partial reduce. Zero grid syncs (batch-partitioned).

#define B_   1024
#define T_   128     // T_ENCO
#define NI_  128     // N_INP
#define H_   256     // N_HID
#define H4_  1024    // 4*N_HID
#define TD_  24      // T_DECO
#define DS_  30      // decoder steps
#define BB   4       // batch rows per workgroup
#define TB   1024    // threads per block

typedef _Float16 hf_t;
typedef _Float16 half8  __attribute__((ext_vector_type(8)));
typedef _Float16 half2v __attribute__((ext_vector_type(2)));

__device__ __forceinline__ float sigm(float x) {
    return __builtin_amdgcn_rcpf(1.0f + __expf(-x));
}
__device__ __forceinline__ float tanh_f(float x) {
    float e = __expf(2.0f * x);
    return 1.0f - 2.0f * __builtin_amdgcn_rcpf(e + 1.0f);
}
__device__ __forceinline__ float fdot2f(half2v a, half2v b, float c) {
#if __has_builtin(__builtin_amdgcn_fdot2)
    return __builtin_amdgcn_fdot2(a, b, c, false);
#else
    return fmaf((float)a.x, (float)b.x, fmaf((float)a.y, (float)b.y, c));
#endif
}
__device__ __forceinline__ float dot8h(half8 w, half8 x, float acc) {
    acc = fdot2f(__builtin_shufflevector(w, w, 0, 1), __builtin_shufflevector(x, x, 0, 1), acc);
    acc = fdot2f(__builtin_shufflevector(w, w, 2, 3), __builtin_shufflevector(x, x, 2, 3), acc);
    acc = fdot2f(__builtin_shufflevector(w, w, 4, 5), __builtin_shufflevector(x, x, 4, 5), acc);
    acc = fdot2f(__builtin_shufflevector(w, w, 6, 7), __builtin_shufflevector(x, x, 6, 7), acc);
    return acc;
}

// ---- f16 weight layout inside d_ws (offsets in halves) ----
// gates G'[(i*1024+o)*8+e] = G[o*K + i*8 + e]
// WE'/WD'[((kq*16+i)*256+k)*8+e] = W[k*512 + kq*128 + i*8 + e]
// UE2'[((kq*4+i)*256+k)*8+e]     = W[k*128 + kq*32  + i*8 + e]
#define W_WE    0u
#define W_UE2   131072u
#define W_EWIH  163840u
#define W_EWHH  294912u
#define W_MWIH  557056u
#define W_MWHH  819200u
#define W_DWIH  1081344u
#define W_DWHH  1343488u
#define W_WD    1605632u
#define W_UD    1736704u
#define SCR_A   2097152u       // Tu [b][j][k] -> Td [b][t][o]  (33,554,432 halves)
#define SCR_B   35651584u      // midb [b][t][k]                (33,554,432 halves)

__global__ void convw_kernel(const float* __restrict__ sWE, const float* __restrict__ sUE2,
                             const float* __restrict__ sEI, const float* __restrict__ sEH,
                             const float* __restrict__ sMI, const float* __restrict__ sMH,
                             const float* __restrict__ sDI, const float* __restrict__ sDH,
                             const float* __restrict__ sWD, const float* __restrict__ sUD,
                             hf_t* __restrict__ dst) {
    const int gtid = blockIdx.x * blockDim.x + threadIdx.x;
    const int gs   = gridDim.x * blockDim.x;
    for (int n = gtid; n < 131072; n += gs) {       // WE'
        int e = n & 7, q = n >> 3, k = q & 255, c = q >> 8, kq = c >> 4, i = c & 15;
        dst[W_WE + n] = (hf_t)sWE[k * 512 + kq * 128 + i * 8 + e];
    }
    for (int n = gtid; n < 32768; n += gs) {        // UE2'
        int e = n & 7, q = n >> 3, k = q & 255, c = q >> 8, kq = c >> 2, i = c & 3;
        dst[W_UE2 + n] = (hf_t)sUE2[k * 128 + kq * 32 + i * 8 + e];
    }
    for (int n = gtid; n < 131072; n += gs) {       // EWIH' (K=128)
        int e = n & 7, q = n >> 3, o = q & 1023, i = q >> 10;
        dst[W_EWIH + n] = (hf_t)sEI[o * 128 + i * 8 + e];
    }
    for (int n = gtid; n < 262144; n += gs) {       // K=256 gates
        int e = n & 7, q = n >> 3, o = q & 1023, i = q >> 10;
        int s = o * 256 + i * 8 + e;
        dst[W_EWHH + n] = (hf_t)sEH[s];
        dst[W_MWIH + n] = (hf_t)sMI[s];
        dst[W_MWHH + n] = (hf_t)sMH[s];
        dst[W_DWIH + n] = (hf_t)sDI[s];
        dst[W_DWHH + n] = (hf_t)sDH[s];
    }
    for (int n = gtid; n < 131072; n += gs) {       // WD'
        int e = n & 7, q = n >> 3, k = q & 255, c = q >> 8, kq = c >> 4, i = c & 15;
        dst[W_WD + n] = (hf_t)sWD[k * 512 + kq * 128 + i * 8 + e];
    }
    for (int n = gtid; n < 65536; n += gs)          // UD plain
        dst[W_UD + n] = (hf_t)sUD[n];
}

// ---- LDS offsets (f32 units) ----
#define O_HC    0        // hf [4][512]  [h;c]
#define O_CF    1024     // f32 [4][256]
#define O_HM    2048     // hf [4][256]
#define O_CMF   2560     // f32 [4][256]
#define O_XRAW  3584     // f32 [4][128]
#define O_XH    4096     // hf [4][128]
#define O_XG    4352     // hf [4][128]
#define O_TA    4608     // f32 [4][256]  tanh(hcxi)
#define O_SPART 5632     // f32 [1024]   (decoder reuses as hful)
#define O_SBUF  6656     // f32 [4][128]
#define O_DINH  7168     // hf [4][256]
#define O_VES   7680     // f32 [256]
#define O_VDS   7936     // f32 [256]
#define O_GBUF  8192     // f32 [8192] partials/gates -> ends 16384

__global__ __launch_bounds__(TB, 4) void dsrnn_kernel(
    const float* __restrict__ inp,
    const float* __restrict__ UeW,  const float* __restrict__ Ueb,
    const float* __restrict__ Ue2b,
    const float* __restrict__ Web,
    const float* __restrict__ VeW,  const float* __restrict__ Veb,
    const float* __restrict__ Udb,
    const float* __restrict__ Wdb,
    const float* __restrict__ VdW,  const float* __restrict__ Vdb,
    const float* __restrict__ ebih, const float* __restrict__ ebhh,
    const float* __restrict__ mbih, const float* __restrict__ mbhh,
    const float* __restrict__ dbih, const float* __restrict__ dbhh,
    const float* __restrict__ rW,   const float* __restrict__ rb,
    const hf_t* __restrict__ wb,
    hf_t* __restrict__ scrA,
    hf_t* __restrict__ scrB,
    float* __restrict__ out)
{
    __shared__ float sm[16384];
    const int tid = threadIdx.x;
    const int b0  = blockIdx.x * BB;

    hf_t*  hc   = (hf_t*)(sm + O_HC);
    float* cf   = sm + O_CF;
    hf_t*  hm   = (hf_t*)(sm + O_HM);
    float* cmf  = sm + O_CMF;
    float* xraw = sm + O_XRAW;
    hf_t*  xh   = (hf_t*)(sm + O_XH);
    hf_t*  xg   = (hf_t*)(sm + O_XG);
    float* TaB  = sm + O_TA;
    float* spart= sm + O_SPART;
    float* sbuf = sm + O_SBUF;
    hf_t*  dinh = (hf_t*)(sm + O_DINH);
    float* hful = sm + O_SPART;      // decoder-phase overlay
    float* ves  = sm + O_VES;
    float* vds  = sm + O_VDS;
    float* gbuf = sm + O_GBUF;

    // ---------- Phase 0: Tu[b][j][k] = tanh(sum_t X[t,j]*UeW[k,t] + Ueb[k]) ----------
    {
        const int j = tid & 127, kq8 = tid >> 7;   // kq8: 0..7, 32 k each
        for (int b = 0; b < BB; ++b) {
            __syncthreads();
            const float* Xg = inp + (size_t)(b0 + b) * T_ * NI_;
            for (int i = tid; i < T_ * NI_; i += TB) sm[i] = Xg[i];
            __syncthreads();
            hf_t* ub = scrA + (size_t)(b0 + b) * NI_ * H_;   // [j][k]
            for (int k0 = kq8 * 32; k0 < kq8 * 32 + 32; k0 += 8) {
                half8 v;
#pragma unroll
                for (int kk = 0; kk < 8; ++kk) {
                    const float* wrow = UeW + (size_t)(k0 + kk) * T_;
                    float acc = Ueb[k0 + kk];
#pragma unroll 4
                    for (int t = 0; t < T_; ++t) acc = fmaf(wrow[t], sm[t * NI_ + j], acc);
                    v[kk] = (hf_t)tanh_f(acc);
                }
                *(half8*)&ub[(size_t)j * H_ + k0] = v;
            }
        }
    }
    __syncthreads();
    for (int i = tid; i < 3584; i += TB) sm[i] = 0.0f;   // zero h/c enc+mid
    if (tid < 256) { ves[tid] = VeW[tid]; vds[tid] = VdW[tid]; }
    __syncthreads();

    // ---------- Fused encoder + mid loop ----------
    for (int t = 0; t < T_; ++t) {
        // (a) load x_t
        if (tid < 512) {
            const int b = tid >> 7, j = tid & 127;
            float v = inp[((size_t)(b0 + b) * T_ + t) * NI_ + j];
            xraw[b * NI_ + j] = v;
            xh[b * NI_ + j]   = (hf_t)v;
        }
        __syncthreads();

        // (b) We.[h;c] + Ue2.x partials, k-quarter split
        {
            const int k = tid & 255, kq = tid >> 8;
            const half8* wWE = (const half8*)(wb + W_WE)  + (size_t)(kq * 16) * 256 + k;
            const half8* wU2 = (const half8*)(wb + W_UE2) + (size_t)(kq * 4)  * 256 + k;
            float a0 = 0.f, a1 = 0.f, a2 = 0.f, a3 = 0.f;
#pragma unroll 8
            for (int i = 0; i < 16; ++i) {
                half8 w = wWE[(size_t)i * 256];
                a0 = dot8h(w, *(const half8*)&hc[0 * 512 + kq * 128 + i * 8], a0);
                a1 = dot8h(w, *(const half8*)&hc[1 * 512 + kq * 128 + i * 8], a1);
                a2 = dot8h(w, *(const half8*)&hc[2 * 512 + kq * 128 + i * 8], a2);
                a3 = dot8h(w, *(const half8*)&hc[3 * 512 + kq * 128 + i * 8], a3);
            }
#pragma unroll
            for (int i = 0; i < 4; ++i) {
                half8 w = wU2[(size_t)i * 256];
                a0 = dot8h(w, *(const half8*)&xh[0 * 128 + kq * 32 + i * 8], a0);
                a1 = dot8h(w, *(const half8*)&xh[1 * 128 + kq * 32 + i * 8], a1);
                a2 = dot8h(w, *(const half8*)&xh[2 * 128 + kq * 32 + i * 8], a2);
                a3 = dot8h(w, *(const half8*)&xh[3 * 128 + kq * 32 + i * 8], a3);
            }
            gbuf[kq * 1024 + 0 * 256 + k] = a0;
            gbuf[kq * 1024 + 1 * 256 + k] = a1;
            gbuf[kq * 1024 + 2 * 256 + k] = a2;
            gbuf[kq * 1024 + 3 * 256 + k] = a3;
        }
        __syncthreads();
        {   // reduce + tanh -> Ta
            const int b = tid >> 8, k = tid & 255;
            float s = gbuf[b * 256 + k] + gbuf[1024 + b * 256 + k]
                    + gbuf[2048 + b * 256 + k] + gbuf[3072 + b * 256 + k]
                    + Web[k] + Ue2b[k];
            TaB[b * 256 + k] = tanh_f(s);
        }
        __syncthreads();

        // (c) scores via tanh identity: t = (Ta+Tu)/(1+Ta*Tu)
        {
            const int b = tid >> 8, r = tid & 255, kh = r >> 7, j = r & 127;
            const half8* up = (const half8*)(scrA + ((size_t)(b0 + b) * NI_ + j) * H_ + kh * 128);
            const float* ta = TaB + b * 256 + kh * 128;
            const float* vw = ves + kh * 128;
            float acc = kh ? 0.f : Veb[0];
#pragma unroll 4
            for (int i = 0; i < 16; ++i) {
                half8 u = up[i];
                float4 t0 = *(const float4*)&ta[i * 8];
                float4 t1 = *(const float4*)&ta[i * 8 + 4];
                float4 v0 = *(const float4*)&vw[i * 8];
                float4 v1 = *(const float4*)&vw[i * 8 + 4];
                const float tt[8] = {t0.x, t0.y, t0.z, t0.w, t1.x, t1.y, t1.z, t1.w};
                const float vv[8] = {v0.x, v0.y, v0.z, v0.w, v1.x, v1.y, v1.z, v1.w};
#pragma unroll
                for (int e = 0; e < 8; ++e) {
                    float tu  = (float)u[e];
                    float num = tt[e] + tu;
                    float den = fmaf(tt[e], tu, 1.0f);
                    acc = fmaf(vv[e] * num, __builtin_amdgcn_rcpf(den), acc);
                }
            }
            spart[tid] = acc;
        }
        __syncthreads();

        // (d) softmax per b (one wave per b), gate x
        if (tid < 256) {
            const int b = tid >> 6, lane = tid & 63;
            const int base = b << 8;
            float sA = spart[base + lane]      + spart[base + 128 + lane];
            float sB = spart[base + 64 + lane] + spart[base + 192 + lane];
            float m = fmaxf(sA, sB);
            for (int d = 1; d < 64; d <<= 1) m = fmaxf(m, __shfl_xor(m, d));
            float eA = __expf(sA - m), eB = __expf(sB - m);
            float ssum = eA + eB;
            for (int d = 1; d < 64; d <<= 1) ssum += __shfl_xor(ssum, d);
            float inv = 1.0f / ssum;
            xg[b * NI_ + lane]      = (hf_t)(xraw[b * NI_ + lane] * eA * inv);
            xg[b * NI_ + lane + 64] = (hf_t)(xraw[b * NI_ + lane + 64] * eB * inv);
        }
        __syncthreads();

        // (e) encoder gates: o-pair x K-half split
        {
            const int op = tid & 511, kq = tid >> 9;
            float a00, a01, a02, a03, a10, a11, a12, a13;
            if (kq == 0) {
                float b0v = ebih[op] + ebhh[op];
                float b1v = ebih[op + 512] + ebhh[op + 512];
                a00 = a01 = a02 = a03 = b0v;
                a10 = a11 = a12 = a13 = b1v;
                const half8* wiA = (const half8*)(wb + W_EWIH) + op;
                const half8* wiB = (const half8*)(wb + W_EWIH) + op + 512;
#pragma unroll 8
                for (int i = 0; i < 16; ++i) {
                    half8 w0 = wiA[(size_t)i * 1024], w1 = wiB[(size_t)i * 1024];
                    half8 x0 = *(const half8*)&xg[0 * 128 + i * 8];
                    half8 x1 = *(const half8*)&xg[1 * 128 + i * 8];
                    half8 x2 = *(const half8*)&xg[2 * 128 + i * 8];
                    half8 x3 = *(const half8*)&xg[3 * 128 + i * 8];
                    a00 = dot8h(w0, x0, a00); a01 = dot8h(w0, x1, a01);
                    a02 = dot8h(w0, x2, a02); a03 = dot8h(w0, x3, a03);
                    a10 = dot8h(w1, x0, a10); a11 = dot8h(w1, x1, a11);
                    a12 = dot8h(w1, x2, a12); a13 = dot8h(w1, x3, a13);
                }
                const half8* whA = (const half8*)(wb + W_EWHH) + op;
                const half8* whB = (const half8*)(wb + W_EWHH) + op + 512;
#pragma unroll 8
                for (int i = 0; i < 8; ++i) {
                    half8 w0 = whA[(size_t)i * 1024], w1 = whB[(size_t)i * 1024];
                    half8 h0v = *(const half8*)&hc[0 * 512 + i * 8];
                    half8 h1v = *(const half8*)&hc[1 * 512 + i * 8];
                    half8 h2v = *(const half8*)&hc[2 * 512 + i * 8];
                    half8 h3v = *(const half8*)&hc[3 * 512 + i * 8];
                    a00 = dot8h(w0, h0v, a00); a01 = dot8h(w0, h1v, a01);
                    a02 = dot8h(w0, h2v, a02); a03 = dot8h(w0, h3v, a03);
                    a10 = dot8h(w1, h0v, a10); a11 = dot8h(w1, h1v, a11);
                    a12 = dot8h(w1, h2v, a12); a13 = dot8h(w1, h3v, a13);
                }
            } else {
                a00 = a01 = a02 = a03 = 0.f;
                a10 = a11 = a12 = a13 = 0.f;
                const half8* whA = (const half8*)(wb + W_EWHH) + op;
                const half8* whB = (const half8*)(wb + W_EWHH) + op + 512;
#pragma unroll 8
                for (int i = 8; i < 32; ++i) {
                    half8 w0 = whA[(size_t)i * 1024], w1 = whB[(size_t)i * 1024];
                    half8 h0v = *(const half8*)&hc[0 * 512 + i * 8];
                    half8 h1v = *(const half8*)&hc[1 * 512 + i * 8];
                    half8 h2v = *(const half8*)&hc[2 * 512 + i * 8];
                    half8 h3v = *(const half8*)&hc[3 * 512 + i * 8];
                    a00 = dot8h(w0, h0v, a00); a01 = dot8h(w0, h1v, a01);
                    a02 = dot8h(w0, h2v, a02); a03 = dot8h(w0, h3v, a03);
                    a10 = dot8h(w1, h0v, a10); a11 = dot8h(w1, h1v, a11);
                    a12 = dot8h(w1, h2v, a12); a13 = dot8h(w1, h3v, a13);
                }
            }
            float* gp = gbuf + kq * 4096;
            gp[0 * 1024 + op] = a00; gp[1 * 1024 + op] = a01;
            gp[2 * 1024 + op] = a02; gp[3 * 1024 + op] = a03;
            gp[0 * 1024 + op + 512] = a10; gp[1 * 1024 + op + 512] = a11;
            gp[2 * 1024 + op + 512] = a12; gp[3 * 1024 + op + 512] = a13;
        }
        __syncthreads();

        // (f) encoder LSTM update
        {
            const int b = tid >> 8, k = tid & 255;
            float gi = gbuf[b * H4_ + k]            + gbuf[4096 + b * H4_ + k];
            float gf = gbuf[b * H4_ + H_ + k]       + gbuf[4096 + b * H4_ + H_ + k];
            float gg = gbuf[b * H4_ + 2 * H_ + k]   + gbuf[4096 + b * H4_ + 2 * H_ + k];
            float go = gbuf[b * H4_ + 3 * H_ + k]   + gbuf[4096 + b * H4_ + 3 * H_ + k];
            float c2 = sigm(gf) * cf[b * H_ + k] + sigm(gi) * tanh_f(gg);
            float h2 = sigm(go) * tanh_f(c2);
            cf[b * H_ + k] = c2;
            hc[b * 512 + k]       = (hf_t)h2;
            hc[b * 512 + 256 + k] = (hf_t)c2;
        }
        __syncthreads();

        // (g) mid gates: o-pair x K-half (kq0: h_enc, kq1: h_mid)
        {
            const int op = tid & 511, kq = tid >> 9;
            float a00, a01, a02, a03, a10, a11, a12, a13;
            if (kq == 0) {
                float b0v = mbih[op] + mbhh[op];
                float b1v = mbih[op + 512] + mbhh[op + 512];
                a00 = a01 = a02 = a03 = b0v;
                a10 = a11 = a12 = a13 = b1v;
                const half8* wA = (const half8*)(wb + W_MWIH) + op;
                const half8* wB = (const half8*)(wb + W_MWIH) + op + 512;
#pragma unroll 8
                for (int i = 0; i < 32; ++i) {
                    half8 w0 = wA[(size_t)i * 1024], w1 = wB[(size_t)i * 1024];
                    half8 h0v = *(const half8*)&hc[0 * 512 + i * 8];
                    half8 h1v = *(const half8*)&hc[1 * 512 + i * 8];
                    half8 h2v = *(const half8*)&hc[2 * 512 + i * 8];
                    half8 h3v = *(const half8*)&hc[3 * 512 + i * 8];
                    a00 = dot8h(w0, h0v, a00); a01 = dot8h(w0, h1v, a01);
                    a02 = dot8h(w0, h2v, a02); a03 = dot8h(w0, h3v, a03);
                    a10 = dot8h(w1, h0v, a10); a11 = dot8h(w1, h1v, a11);
                    a12 = dot8h(w1, h2v, a12); a13 = dot8h(w1, h3v, a13);
                }
            } else {
                a00 = a01 = a02 = a03 = 0.f;
                a10 = a11 = a12 = a13 = 0.f;
                const half8* wA = (const half8*)(wb + W_MWHH) + op;
                const half8* wB = (const half8*)(wb + W_MWHH) + op + 512;
#pragma unroll 8
                for (int i = 0; i < 32; ++i) {
                    half8 w0 = wA[(size_t)i * 1024], w1 = wB[(size_t)i * 1024];
                    half8 h0v = *(const half8*)&hm[0 * 256 + i * 8];
                    half8 h1v = *(const half8*)&hm[1 * 256 + i * 8];
                    half8 h2v = *(const half8*)&hm[2 * 256 + i * 8];
                    half8 h3v = *(const half8*)&hm[3 * 256 + i * 8];
                    a00 = dot8h(w0, h0v, a00); a01 = dot8h(w0, h1v, a01);
                    a02 = dot8h(w0, h2v, a02); a03 = dot8h(w0, h3v, a03);
                    a10 = dot8h(w1, h0v, a10); a11 = dot8h(w1, h1v, a11);
                    a12 = dot8h(w1, h2v, a12); a13 = dot8h(w1, h3v, a13);
                }
            }
            float* gp = gbuf + kq * 4096;
            gp[0 * 1024 + op] = a00; gp[1 * 1024 + op] = a01;
            gp[2 * 1024 + op] = a02; gp[3 * 1024 + op] = a03;
            gp[0 * 1024 + op + 512] = a10; gp[1 * 1024 + op + 512] = a11;
            gp[2 * 1024 + op + 512] = a12; gp[3 * 1024 + op + 512] = a13;
        }
        __syncthreads();

        // (h) mid LSTM update + store mid
        {
            const int b = tid >> 8, k = tid & 255;
            float gi = gbuf[b * H4_ + k]            + gbuf[4096 + b * H4_ + k];
            float gf = gbuf[b * H4_ + H_ + k]       + gbuf[4096 + b * H4_ + H_ + k];
            float gg = gbuf[b * H4_ + 2 * H_ + k]   + gbuf[4096 + b * H4_ + 2 * H_ + k];
            float go = gbuf[b * H4_ + 3 * H_ + k]   + gbuf[4096 + b * H4_ + 3 * H_ + k];
            float c2 = sigm(gf) * cmf[b * H_ + k] + sigm(gi) * tanh_f(gg);
            float h2 = sigm(go) * tanh_f(c2);
            cmf[b * H_ + k] = c2;
            hm[b * 256 + k] = (hf_t)h2;
            scrB[((size_t)(b0 + b) * T_ + t) * H_ + k] = (hf_t)h2;
        }
        __syncthreads();
    }

    // ---------- Td pass: Td[b][t][o] = tanh(UdW[o,:].mid[b,t,:] + Udb[o]) ----------
    {
        const int b = tid >> 8, r = tid & 255, oh = r >> 7, tt = r & 127;
        const half8* mrow = (const half8*)(scrB + ((size_t)(b0 + b) * T_ + tt) * H_);
        half8 m[32];
#pragma unroll
        for (int i = 0; i < 32; ++i) m[i] = mrow[i];
        const half8* udw = (const half8*)(wb + W_UD);
        for (int o0 = oh * 128; o0 < oh * 128 + 128; o0 += 8) {
            half8 v;
#pragma unroll
            for (int oo = 0; oo < 8; ++oo) {
                const half8* ur = udw + (size_t)(o0 + oo) * 32;
                float acc = Udb[o0 + oo];
#pragma unroll 8
                for (int i = 0; i < 32; ++i) acc = dot8h(ur[i], m[i], acc);
                v[oo] = (hf_t)tanh_f(acc);
            }
            *(half8*)&scrA[((size_t)(b0 + b) * T_ + tt) * H_ + o0] = v;
        }
    }
    __syncthreads();
    for (int i = tid; i < 2048; i += TB) sm[i] = 0.0f;   // zero dec h/c
    __syncthreads();

    // ---------- Decoder ----------
    for (int s = 0; s < DS_; ++s) {
        // (a') Wd.[h;c] partials, k-quarter split -> Ta = tanh
        {
            const int k = tid & 255, kq = tid >> 8;
            const half8* wWD = (const half8*)(wb + W_WD) + (size_t)(kq * 16) * 256 + k;
            float a0 = 0.f, a1 = 0.f, a2 = 0.f, a3 = 0.f;
#pragma unroll 8
            for (int i = 0; i < 16; ++i) {
                half8 w = wWD[(size_t)i * 256];
                a0 = dot8h(w, *(const half8*)&hc[0 * 512 + kq * 128 + i * 8], a0);
                a1 = dot8h(w, *(const half8*)&hc[1 * 512 + kq * 128 + i * 8], a1);
                a2 = dot8h(w, *(const half8*)&hc[2 * 512 + kq * 128 + i * 8], a2);
                a3 = dot8h(w, *(const half8*)&hc[3 * 512 + kq * 128 + i * 8], a3);
            }
            gbuf[kq * 1024 + 0 * 256 + k] = a0;
            gbuf[kq * 1024 + 1 * 256 + k] = a1;
            gbuf[kq * 1024 + 2 * 256 + k] = a2;
            gbuf[kq * 1024 + 3 * 256 + k] = a3;
        }
        __syncthreads();
        {
            const int b = tid >> 8, k = tid & 255;
            float sv = gbuf[b * 256 + k] + gbuf[1024 + b * 256 + k]
                     + gbuf[2048 + b * 256 + k] + gbuf[3072 + b * 256 + k]
                     + Wdb[k];
            TaB[b * 256 + k] = tanh_f(sv);
        }
        __syncthreads();

        // (b') temporal scores via identity (no softmax)
        {
            const int b = tid >> 8, r = tid & 255, kh = r >> 7, j = r & 127;
            const half8* up = (const half8*)(scrA + ((size_t)(b0 + b) * T_ + j) * H_ + kh * 128);
            const float* ta = TaB + b * 256 + kh * 128;
            const float* vw = vds + kh * 128;
            float acc = kh ? 0.f : Vdb[0];
#pragma unroll 4
            for (int i = 0; i < 16; ++i) {
                half8 u = up[i];
                float4 t0 = *(const float4*)&ta[i * 8];
                float4 t1 = *(const float4*)&ta[i * 8 + 4];
                float4 v0 = *(const float4*)&vw[i * 8];
                float4 v1 = *(const float4*)&vw[i * 8 + 4];
                const float tt[8] = {t0.x, t0.y, t0.z, t0.w, t1.x, t1.y, t1.z, t1.w};
                const float vv[8] = {v0.x, v0.y, v0.z, v0.w, v1.x, v1.y, v1.z, v1.w};
#pragma unroll
                for (int e = 0; e < 8; ++e) {
                    float tu  = (float)u[e];
                    float num = tt[e] + tu;
                    float den = fmaf(tt[e], tu, 1.0f);
                    acc = fmaf(vv[e] * num, __builtin_amdgcn_rcpf(den), acc);
                }
            }
            spart[tid] = acc;
        }
        __syncthreads();
        if (tid < 512) {
            const int b = tid >> 7, j = tid & 127;
            sbuf[b * T_ + j] = spart[(b << 8) + j] + spart[(b << 8) + 128 + j];
        }
        __syncthreads();

        // (d') dec_in[b,h] = sum_j t[b,j] * mid[b,j,h]
        {
            const int b = tid >> 8, h = tid & 255;
            const hf_t* mp = scrB + (size_t)(b0 + b) * T_ * H_ + h;
            float acc = 0.0f;
            for (int j = 0; j < T_; ++j)
                acc = fmaf(sbuf[b * T_ + j], (float)mp[(size_t)j * H_], acc);
            dinh[b * 256 + h] = (hf_t)acc;
        }
        __syncthreads();

        // (e') decoder gates: o-pair x K-half (kq0: dec_in, kq1: h)
        {
            const int op = tid & 511, kq = tid >> 9;
            float a00, a01, a02, a03, a10, a11, a12, a13;
            if (kq == 0) {
                float b0v = dbih[op] + dbhh[op];
                float b1v = dbih[op + 512] + dbhh[op + 512];
                a00 = a01 = a02 = a03 = b0v;
                a10 = a11 = a12 = a13 = b1v;
                const half8* wA = (const half8*)(wb + W_DWIH) + op;
                const half8* wB = (const half8*)(wb + W_DWIH) + op + 512;
#pragma unroll 8
                for (int i = 0; i < 32; ++i) {
                    half8 w0 = wA[(size_t)i * 1024], w1 = wB[(size_t)i * 1024];
                    half8 x0 = *(const half8*)&dinh[0 * 256 + i * 8];
                    half8 x1 = *(const half8*)&dinh[1 * 256 + i * 8];
                    half8 x2 = *(const half8*)&dinh[2 * 256 + i * 8];
                    half8 x3 = *(const half8*)&dinh[3 * 256 + i * 8];
                    a00 = dot8h(w0, x0, a00); a01 = dot8h(w0, x1, a01);
                    a02 = dot8h(w0, x2, a02); a03 = dot8h(w0, x3, a03);
                    a10 = dot8h(w1, x0, a10); a11 = dot8h(w1, x1, a11);
                    a12 = dot8h(w1, x2, a12); a13 = dot8h(w1, x3, a13);
                }
            } else {
                a00 = a01 = a02 = a03 = 0.f;
                a10 = a11 = a12 = a13 = 0.f;
                const half8* wA = (const half8*)(wb + W_DWHH) + op;
                const half8* wB = (const half8*)(wb + W_DWHH) + op + 512;
#pragma unroll 8
                for (int i = 0; i < 32; ++i) {
                    half8 w0 = wA[(size_t)i * 1024], w1 = wB[(size_t)i * 1024];
                    half8 h0v = *(const half8*)&hc[0 * 512 + i * 8];
                    half8 h1v = *(const half8*)&hc[1 * 512 + i * 8];
                    half8 h2v = *(const half8*)&hc[2 * 512 + i * 8];
                    half8 h3v = *(const half8*)&hc[3 * 512 + i * 8];
                    a00 = dot8h(w0, h0v, a00); a01 = dot8h(w0, h1v, a01);
                    a02 = dot8h(w0, h2v, a02); a03 = dot8h(w0, h3v, a03);
                    a10 = dot8h(w1, h0v, a10); a11 = dot8h(w1, h1v, a11);
                    a12 = dot8h(w1, h2v, a12); a13 = dot8h(w1, h3v, a13);
                }
            }
            float* gp = gbuf + kq * 4096;
            gp[0 * 1024 + op] = a00; gp[1 * 1024 + op] = a01;
            gp[2 * 1024 + op] = a02; gp[3 * 1024 + op] = a03;
            gp[0 * 1024 + op + 512] = a10; gp[1 * 1024 + op + 512] = a11;
            gp[2 * 1024 + op + 512] = a12; gp[3 * 1024 + op + 512] = a13;
        }
        __syncthreads();

        // (f') decoder LSTM update
        {
            const int b = tid >> 8, k = tid & 255;
            float gi = gbuf[b * H4_ + k]            + gbuf[4096 + b * H4_ + k];
            float gf = gbuf[b * H4_ + H_ + k]       + gbuf[4096 + b * H4_ + H_ + k];
            float gg = gbuf[b * H4_ + 2 * H_ + k]   + gbuf[4096 + b * H4_ + 2 * H_ + k];
            float go = gbuf[b * H4_ + 3 * H_ + k]   + gbuf[4096 + b * H4_ + 3 * H_ + k];
            float c2 = sigm(gf) * cf[b * H_ + k] + sigm(gi) * tanh_f(gg);
            float h2 = sigm(go) * tanh_f(c2);
            cf[b * H_ + k] = c2;
            hc[b * 512 + k]       = (hf_t)h2;
            hc[b * 512 + 256 + k] = (hf_t)c2;
            hful[b * H_ + k] = h2;
        }
        __syncthreads();

        // (g') out[b, s-6] = rW.h + rb
        if (s >= 6 && tid < 256) {
            const int b = tid >> 6, lane = tid & 63;
            float p = rW[lane]       * hful[b * H_ + lane]
                    + rW[lane + 64]  * hful[b * H_ + lane + 64]
                    + rW[lane + 128] * hful[b * H_ + lane + 128]
                    + rW[lane + 192] * hful[b * H_ + lane + 192];
            for (int d = 1; d < 64; d <<= 1) p += __shfl_xor(p, d);
            if (lane == 0) out[(size_t)(b0 + b) * TD_ + (s - 6)] = p + rb[0];
        }
        __syncthreads();
    }
}

extern "C" void kernel_launch(void* const* d_in, const int* in_sizes, int n_in,
                              void* d_out, int out_size, void* d_ws, size_t ws_size,
                              hipStream_t stream) {
    const float* inp  = (const float*)d_in[0];
    const float* UeW  = (const float*)d_in[2];
    const float* Ueb  = (const float*)d_in[3];
    const float* Ue2W = (const float*)d_in[4];
    const float* Ue2b = (const float*)d_in[5];
    const float* WeW  = (const float*)d_in[6];
    const float* Web  = (const float*)d_in[7];
    const float* VeW  = (const float*)d_in[8];
    const float* Veb  = (const float*)d_in[9];
    const float* UdW  = (const float*)d_in[10];
    const float* Udb  = (const float*)d_in[11];
    const float* WdW  = (const float*)d_in[12];
    const float* Wdb  = (const float*)d_in[13];
    const float* VdW  = (const float*)d_in[14];
    const float* Vdb  = (const float*)d_in[15];
    const float* eWih = (const float*)d_in[16];
    const float* eWhh = (const float*)d_in[17];
    const float* ebih = (const float*)d_in[18];
    const float* ebhh = (const float*)d_in[19];
    const float* mWih = (const float*)d_in[20];
    const float* mWhh = (const float*)d_in[21];
    const float* mbih = (const float*)d_in[22];
    const float* mbhh = (const float*)d_in[23];
    const float* dWih = (const float*)d_in[24];
    const float* dWhh = (const float*)d_in[25];
    const float* dbih = (const float*)d_in[26];
    const float* dbhh = (const float*)d_in[27];
    const float* rW   = (const float*)d_in[28];
    const float* rb   = (const float*)d_in[29];

    hf_t* wsb  = (hf_t*)d_ws;
    hf_t* scrA = wsb + SCR_A;
    hf_t* scrB = wsb + SCR_B;

    convw_kernel<<<512, 256, 0, stream>>>(WeW, Ue2W, eWih, eWhh, mWih, mWhh,
                                          dWih, dWhh, WdW, UdW, wsb);

    dsrnn_kernel<<<B_ / BB, TB, 0, stream>>>(
        inp, UeW, Ueb, Ue2b, Web, VeW, Veb, Udb, Wdb, VdW, Vdb,
        ebih, ebhh, mbih, mbhh, dbih, dbhh, rW, rb,
        wsb, scrA, scrB, (float*)d_out);
}